// Round 3
// baseline (102.672 us; speedup 1.0000x reference)
//
#include <hip/hip_runtime.h>
#include <hip/hip_bf16.h>
#include <stdint.h>

#define KP    416        // padded rank (396->416) and padded wemb (400->416)
#define RANKD 396
#define WEMB  400
#define TEMB  20
#define TAGS  25
#define BATCH 16
#define LSEQ  128
#define MROWS 126        // L-2
#define NM    2016       // 16*126
#define NMP   2048
#define ABC   15625
#define ABCP  15872      // 62*256
#define SCALE 0.050251890762960605f   // 1/sqrt(396)

typedef __attribute__((ext_vector_type(8))) short short8;
typedef __attribute__((ext_vector_type(4))) float f32x4;

// workspace layout (bytes)
#define OFF_T01  0                         // 2048*416*2      = 1,703,936
#define OFF_T02  1703936                   // 15872*416*2     = 13,205,504
#define OFF_WORD 14909440                  // 16*128*416*2    = 1,703,936
#define OFF_WT   16613376                  // 3*416*416*2     = 1,038,336
#define OFF_G    17651712                  // 3*25*416*4      = 124,800

#define GLOAD_LDS16(gp, lp) \
  __builtin_amdgcn_global_load_lds((const __attribute__((address_space(1))) uint32_t*)(gp), \
                                   (__attribute__((address_space(3))) uint32_t*)(lp), 16, 0, 0)

__device__ __forceinline__ uint16_t f2bf(float f) {
    union { float f; uint32_t u; } v; v.f = f;
    uint32_t u = v.u;
    return (uint16_t)((u + 0x7FFFu + ((u >> 16) & 1u)) >> 16);  // RNE
}

// ---- prep: word->bf16 pad | W->Wt bf16 pad | g4/g5/g6 fp32 (fused by block range)
#define J1_BLK 3328   // 16*128*416/256
#define J2_BLK 2028   // 3*416*416/256
#define J3_BLK 122    // ceil(3*25*416/256)
__global__ void k_prep(const float* __restrict__ word,
                       const float* __restrict__ W1, const float* __restrict__ W2,
                       const float* __restrict__ W3, const float* __restrict__ tag,
                       const float* __restrict__ T1, const float* __restrict__ T2,
                       const float* __restrict__ T3,
                       uint16_t* __restrict__ wordb, uint16_t* __restrict__ wt,
                       float* __restrict__ g) {
    int bx = blockIdx.x;
    if (bx < J1_BLK) {
        int idx = bx * 256 + threadIdx.x;
        int e = idx % KP, row = idx / KP;
        wordb[idx] = f2bf((e < WEMB) ? word[row * WEMB + e] : 0.f);
    } else if (bx < J1_BLK + J2_BLK) {
        int idx = (bx - J1_BLK) * 256 + threadIdx.x;
        int j = idx / (KP * KP);
        int rem = idx % (KP * KP);
        int k = rem / KP, e = rem % KP;
        const float* W = (j == 0) ? W1 : (j == 1) ? W2 : W3;
        wt[idx] = f2bf((k < RANKD && e < WEMB) ? W[e * RANKD + k] : 0.f);
    } else {
        int idx = (bx - J1_BLK - J2_BLK) * 256 + threadIdx.x;
        if (idx >= 3 * TAGS * KP) return;
        int j = idx / (TAGS * KP);
        int rem = idx % (TAGS * KP);
        int a = rem / KP, k = rem % KP;
        const float* T = (j == 0) ? T1 : (j == 1) ? T2 : T3;
        float s = 0.f;
        if (k < RANKD) {
            for (int e = 0; e < TEMB; ++e) s += tag[a * TEMB + e] * T[e * RANKD + k];
        }
        g[idx] = s;
    }
}

// ---- mid: t01 build (MFMA) blocks [0,896) | t02 build blocks [896,...)
#define T01_BLK 896    // 128 nm-tiles * 7 k-groups
#define T02_BLK 3224   // 15872*52/256
__global__ __launch_bounds__(256) void k_mid(const uint16_t* __restrict__ word,
                                             const uint16_t* __restrict__ wt,
                                             const float* __restrict__ g,
                                             uint16_t* __restrict__ t01,
                                             uint16_t* __restrict__ t02) {
    int bx = blockIdx.x;
    if (bx < T01_BLK) {
        int wid = threadIdx.x >> 6, lane = threadIdx.x & 63;
        int nmtile = bx & 127;
        int ktile = (bx >> 7) * 4 + wid;
        if (ktile >= KP / 16) return;
        int col_l = lane & 15, kblk = lane >> 4;
        int colk = ktile * 16 + col_l;
        f32x4 acc1 = {0.f, 0.f, 0.f, 0.f}, acc2 = acc1, acc3 = acc1;
        if (nmtile < NM / 16) {
            int nm_a = nmtile * 16 + col_l;
            int n = nm_a / MROWS, m = nm_a % MROWS;
            const uint16_t* arow = word + (size_t)(n * LSEQ + m) * KP;
            const uint16_t* b1 = wt + (size_t)colk * KP;
            const uint16_t* b2 = wt + (size_t)KP * KP + (size_t)colk * KP;
            const uint16_t* b3 = wt + (size_t)2 * KP * KP + (size_t)colk * KP;
            for (int e0 = 0; e0 < KP; e0 += 32) {
                int eo = e0 + kblk * 8;
                short8 a0 = *(const short8*)(arow + eo);
                short8 a1 = *(const short8*)(arow + KP + eo);
                short8 a2 = *(const short8*)(arow + 2 * KP + eo);
                short8 v1 = *(const short8*)(b1 + eo);
                short8 v2 = *(const short8*)(b2 + eo);
                short8 v3 = *(const short8*)(b3 + eo);
                acc1 = __builtin_amdgcn_mfma_f32_16x16x32_bf16(a0, v1, acc1, 0, 0, 0);
                acc2 = __builtin_amdgcn_mfma_f32_16x16x32_bf16(a1, v2, acc2, 0, 0, 0);
                acc3 = __builtin_amdgcn_mfma_f32_16x16x32_bf16(a2, v3, acc3, 0, 0, 0);
            }
        }
        for (int r = 0; r < 4; ++r) {
            int row = nmtile * 16 + kblk * 4 + r;
            float v = acc1[r] * acc2[r] * acc3[r] * SCALE;
            t01[(size_t)row * KP + colk] = f2bf(v);
        }
    } else {
        int idx = (bx - T01_BLK) * 256 + threadIdx.x;
        int abc = idx / (KP / 8), kc = idx % (KP / 8);
        int k0 = kc * 8;
        short8 o;
        if (abc < ABC) {
            int a = abc / 625, rem = abc % 625, b = rem / 25, c = rem % 25;
            const float4* ga = (const float4*)(g + (size_t)a * KP + k0);
            const float4* gb = (const float4*)(g + (size_t)TAGS * KP + (size_t)b * KP + k0);
            const float4* gc = (const float4*)(g + (size_t)2 * TAGS * KP + (size_t)c * KP + k0);
            float4 a0 = ga[0], a1 = ga[1];
            float4 b0 = gb[0], b1 = gb[1];
            float4 c0 = gc[0], c1 = gc[1];
            o[0] = (short)f2bf(a0.x * b0.x * c0.x);
            o[1] = (short)f2bf(a0.y * b0.y * c0.y);
            o[2] = (short)f2bf(a0.z * b0.z * c0.z);
            o[3] = (short)f2bf(a0.w * b0.w * c0.w);
            o[4] = (short)f2bf(a1.x * b1.x * c1.x);
            o[5] = (short)f2bf(a1.y * b1.y * c1.y);
            o[6] = (short)f2bf(a1.z * b1.z * c1.z);
            o[7] = (short)f2bf(a1.w * b1.w * c1.w);
        } else {
            for (int t = 0; t < 8; ++t) o[t] = 0;
        }
        *(short8*)(t02 + (size_t)abc * KP + k0) = o;
    }
}

// ---- final: score[2016][15625] = t01 @ t02^T
// 256x256 tile, BK=32, 8 waves (2Mx4N, wave-tile 128x64), 4-deep LDS ring,
// counted vmcnt (T4), 2 phases/K-tile (T3), setprio (T5), XCD swizzle (T1).
// LDS k-slot-major [ks][256][8] -> conflict-free ds_read_b128 (pre-swizzled
// global source, linear gload_lds dest).
__global__ __launch_bounds__(512, 2) void k_final(const uint16_t* __restrict__ t01,
                                                  const uint16_t* __restrict__ t02,
                                                  float* __restrict__ out) {
    __shared__ __align__(16) uint16_t ldsA[4][8192];   // 4 bufs x 16 KB
    __shared__ __align__(16) uint16_t ldsB[4][8192];
    const int tid = threadIdx.x;
    const int wid = tid >> 6, lane = tid & 63;
    const int col_l = lane & 15, kblk = lane >> 4;

    // XCD-aware bijective swizzle: 496 blocks = 62 x 8 XCDs
    const int bid = blockIdx.x;
    const int swz = (bid & 7) * 62 + (bid >> 3);
    const int mb = swz & 7, nb = swz >> 3;          // 8 M-blocks, 62 N-blocks
    const int brow = mb * 256, bcol = nb * 256;

    const int wrow = (wid >> 2) * 128, wcol = (wid & 3) * 64;

    // staging: per K-tile, A-tile 256x32 bf16 = 16KB = 2 chunks; chunk c covers
    // ks-planes {2c,2c+1}. lane -> (row = tid&255, ks = 2c + (tid>>8)).
    const int rowS = tid & 255, ksS = tid >> 8;
    const uint16_t* gA0 = t01 + (size_t)(brow + rowS) * KP + ksS * 8;   // chunk 0
    const uint16_t* gA1 = gA0 + 16;                                     // chunk 1 (ks+2)
    const uint16_t* gB0 = t02 + (size_t)(bcol + rowS) * KP + ksS * 8;
    const uint16_t* gB1 = gB0 + 16;
    const int c0 = wid * 512;            // wave-uniform LDS elem base, chunk 0
    const int c1 = 4096 + wid * 512;     // chunk 1

    f32x4 acc[8][4];
#pragma unroll
    for (int m = 0; m < 8; ++m)
#pragma unroll
        for (int n = 0; n < 4; ++n)
            acc[m][n] = (f32x4){0.f, 0.f, 0.f, 0.f};

    // prologue: stage K-tiles 0,1,2 (12 loads/wave); wait tile 0 (keep 8 in flight)
#pragma unroll
    for (int t = 0; t < 3; ++t) {
        GLOAD_LDS16(gA0 + t * 32, &ldsA[t][c0]);
        GLOAD_LDS16(gA1 + t * 32, &ldsA[t][c1]);
        GLOAD_LDS16(gB0 + t * 32, &ldsB[t][c0]);
        GLOAD_LDS16(gB1 + t * 32, &ldsB[t][c1]);
    }
    asm volatile("s_waitcnt vmcnt(8)" ::: "memory");
    __builtin_amdgcn_s_barrier();

    const int NT = KP / 32;   // 13
#pragma unroll
    for (int kt = 0; kt < NT; ++kt) {
        const int buf = kt & 3, nbuf = (kt + 3) & 3;
        const uint16_t* bA = ldsA[buf];
        const uint16_t* bB = ldsB[buf];
        const bool st = (kt + 3) < NT;

        // ---- phase A: frags m0-3 x n0-3 ----
        short8 bF[4], aF[4];
#pragma unroll
        for (int n = 0; n < 4; ++n)
            bF[n] = *(const short8*)(bB + kblk * 2048 + (wcol + n * 16 + col_l) * 8);
#pragma unroll
        for (int m = 0; m < 4; ++m)
            aF[m] = *(const short8*)(bA + kblk * 2048 + (wrow + m * 16 + col_l) * 8);
        if (st) {
            GLOAD_LDS16(gA0 + (kt + 3) * 32, &ldsA[nbuf][c0]);
            GLOAD_LDS16(gA1 + (kt + 3) * 32, &ldsA[nbuf][c1]);
        }
        __builtin_amdgcn_s_barrier();
        asm volatile("s_waitcnt lgkmcnt(0)" ::: "memory");
        __builtin_amdgcn_sched_barrier(0);
        __builtin_amdgcn_s_setprio(1);
#pragma unroll
        for (int m = 0; m < 4; ++m)
#pragma unroll
            for (int n = 0; n < 4; ++n)
                acc[m][n] = __builtin_amdgcn_mfma_f32_16x16x32_bf16(aF[m], bF[n], acc[m][n], 0, 0, 0);
        __builtin_amdgcn_s_setprio(0);
        __builtin_amdgcn_s_barrier();

        // ---- phase B: frags m4-7 x n0-3 (B held in regs) ----
        short8 aG[4];
#pragma unroll
        for (int m = 0; m < 4; ++m)
            aG[m] = *(const short8*)(bA + kblk * 2048 + (wrow + (m + 4) * 16 + col_l) * 8);
        if (st) {
            GLOAD_LDS16(gB0 + (kt + 3) * 32, &ldsB[nbuf][c0]);
            GLOAD_LDS16(gB1 + (kt + 3) * 32, &ldsB[nbuf][c1]);
        }
        __builtin_amdgcn_s_barrier();
        asm volatile("s_waitcnt lgkmcnt(0)" ::: "memory");
        __builtin_amdgcn_sched_barrier(0);
        __builtin_amdgcn_s_setprio(1);
#pragma unroll
        for (int m = 0; m < 4; ++m)
#pragma unroll
            for (int n = 0; n < 4; ++n)
                acc[m + 4][n] = __builtin_amdgcn_mfma_f32_16x16x32_bf16(aG[m], bF[n], acc[m + 4][n], 0, 0, 0);
        __builtin_amdgcn_s_setprio(0);
        // counted end-of-tile wait: tile kt+1 resident; stages kt+2,kt+3 stay in flight
        if (kt <= NT - 4)      { asm volatile("s_waitcnt vmcnt(8)" ::: "memory"); }
        else if (kt == NT - 3) { asm volatile("s_waitcnt vmcnt(4)" ::: "memory"); }
        else if (kt == NT - 2) { asm volatile("s_waitcnt vmcnt(0)" ::: "memory"); }
        if (kt < NT - 1) __builtin_amdgcn_s_barrier();
    }

    // epilogue: fp32 stores
#pragma unroll
    for (int m = 0; m < 8; ++m) {
        int row_b = brow + wrow + m * 16 + kblk * 4;
#pragma unroll
        for (int n = 0; n < 4; ++n) {
            int col = bcol + wcol + n * 16 + col_l;
            if (col < ABC) {
#pragma unroll
                for (int r = 0; r < 4; ++r) {
                    int row = row_b + r;
                    if (row < NM) out[(size_t)row * ABC + col] = acc[m][n][r];
                }
            }
        }
    }
}

extern "C" void kernel_launch(void* const* d_in, const int* in_sizes, int n_in,
                              void* d_out, int out_size, void* d_ws, size_t ws_size,
                              hipStream_t stream) {
    const float* word = (const float*)d_in[0];
    const float* tag  = (const float*)d_in[1];
    const float* W1   = (const float*)d_in[2];
    const float* W2   = (const float*)d_in[3];
    const float* W3   = (const float*)d_in[4];
    const float* T1   = (const float*)d_in[5];
    const float* T2   = (const float*)d_in[6];
    const float* T3   = (const float*)d_in[7];
    float* out = (float*)d_out;
    char* ws = (char*)d_ws;

    uint16_t* t01   = (uint16_t*)(ws + OFF_T01);
    uint16_t* t02   = (uint16_t*)(ws + OFF_T02);
    uint16_t* wordb = (uint16_t*)(ws + OFF_WORD);
    uint16_t* wt    = (uint16_t*)(ws + OFF_WT);
    float*    g     = (float*)(ws + OFF_G);

    k_prep<<<J1_BLK + J2_BLK + J3_BLK, 256, 0, stream>>>(word, W1, W2, W3, tag,
                                                         T1, T2, T3, wordb, wt, g);
    k_mid<<<T01_BLK + T02_BLK, 256, 0, stream>>>(wordb, wt, g, t01, t02);
    k_final<<<NMP / 256 * (ABCP / 256), 512, 0, stream>>>(t01, t02, out);
}